// Round 5
// baseline (316.200 us; speedup 1.0000x reference)
//
#include <hip/hip_runtime.h>
#include <hip/hip_bf16.h>

typedef __bf16 bf16_t;
typedef bf16_t bf16x8 __attribute__((ext_vector_type(8)));
typedef bf16_t bf16x4 __attribute__((ext_vector_type(4)));
typedef float f32x4 __attribute__((ext_vector_type(4)));
typedef short short4_ __attribute__((ext_vector_type(4)));

#define SEQ    2048
#define DHEAD  64
#define DMODEL 1024
#define BHN    64   // B*H
#define LOG2E  1.4426950408889634f
#define NEGBIG (-1e30f)
#define MASKV  (-1e38f)

__device__ __forceinline__ f32x4 mfma16(bf16x8 a, bf16x8 b, f32x4 c) {
  return __builtin_amdgcn_mfma_f32_16x16x32_bf16(a, b, c, 0, 0, 0);
}

// K=16 bf16 MFMA (2-reg operands). NOTE: __has_builtin(amdgcn builtins) is
// FALSE in the host pass — must guard with __HIP_DEVICE_COMPILE__ (R4 lesson).
__device__ __forceinline__ f32x4 mfma_k16(bf16x4 a, bf16x4 b, f32x4 c) {
#if defined(__HIP_DEVICE_COMPILE__)
#if __has_builtin(__builtin_amdgcn_mfma_f32_16x16x16bf16_1k)
  return __builtin_amdgcn_mfma_f32_16x16x16bf16_1k(
      __builtin_bit_cast(short4_, a), __builtin_bit_cast(short4_, b), c, 0, 0, 0);
#else
  // v_mfma_f32_16x16x16_bf16: valid gfx950 (cdna4_isa.md §10); unified VGPR file
  f32x4 d;
  asm("v_mfma_f32_16x16x16_bf16 %0, %1, %2, %3"
      : "=v"(d) : "v"(a), "v"(b), "v"(c));
  return d;
#endif
#else
  (void)a; (void)b;
  return c;  // host-pass parse placeholder (never executed)
#endif
}

// ---------------------------------------------------------------------------
// Kernel 1: per-head QKV projection. Single-barrier structure: stage x AND all
// three W tensors first (all global loads in flight together), one sync, then
// three barrier-free compute loops. Outputs: Qw [bh][s][64] (pre-scaled by
// log2e/8), Kw [bh][s][64], VTw [bh][64][s]; all bf16, vectorized stores.
// ---------------------------------------------------------------------------
__global__ __launch_bounds__(256) void qkv_kernel(
    const float* __restrict__ x,
    const float* __restrict__ Wq, const float* __restrict__ bq,
    const float* __restrict__ Wk, const float* __restrict__ bk,
    const float* __restrict__ Wv, const float* __restrict__ bv,
    bf16_t* __restrict__ Qw, bf16_t* __restrict__ Kw, bf16_t* __restrict__ VTw) {
  __shared__ __align__(16) char x_lds[256 * 128];  // 256 rows x 64 bf16, swizzled
  __shared__ __align__(16) char w_lds[3][8192];    // WT[e][d] bf16 swizzled, per tensor

  const int bh = blockIdx.y;
  const int b = bh >> 4, h = bh & 15;
  const int s0 = blockIdx.x * 256;
  const int t = threadIdx.x;
  const int w = t >> 6, lane = t & 63;
  const int lo = lane & 15, g = lane >> 4;

  // stage all three W (transposed to WT[e][d], bf16, swizzled)
#pragma unroll
  for (int wi = 0; wi < 3; ++wi) {
    const float* Wp = (wi == 0) ? Wq : (wi == 1) ? Wk : Wv;
    const int d = t >> 2, e0 = (t & 3) * 16;
    const float* wp = Wp + (size_t)(h * 64 + d) * 64 + e0;
    const float4 f0 = *(const float4*)(wp);
    const float4 f1 = *(const float4*)(wp + 4);
    const float4 f2 = *(const float4*)(wp + 8);
    const float4 f3 = *(const float4*)(wp + 12);
    float vals[16];
    vals[0] = f0.x; vals[1] = f0.y; vals[2] = f0.z; vals[3] = f0.w;
    vals[4] = f1.x; vals[5] = f1.y; vals[6] = f1.z; vals[7] = f1.w;
    vals[8] = f2.x; vals[9] = f2.y; vals[10] = f2.z; vals[11] = f2.w;
    vals[12] = f3.x; vals[13] = f3.y; vals[14] = f3.z; vals[15] = f3.w;
#pragma unroll
    for (int j = 0; j < 16; ++j) {
      const int e = e0 + j;
      *(bf16_t*)(w_lds[wi] + e * 128 + ((2 * d) ^ ((e & 7) << 4))) = (bf16_t)vals[j];
    }
  }
  // stage x head-slice (256 rows x 64) as bf16, swizzled
#pragma unroll
  for (int p = 0; p < 8; ++p) {
    const int row = p * 32 + (t >> 3);
    const int c = t & 7;
    const float* xp = x + ((size_t)(b * SEQ + s0 + row)) * DMODEL + h * DHEAD + c * 8;
    const float4 f0 = *(const float4*)xp;
    const float4 f1 = *(const float4*)(xp + 4);
    bf16x8 v;
    v[0] = (bf16_t)f0.x; v[1] = (bf16_t)f0.y; v[2] = (bf16_t)f0.z; v[3] = (bf16_t)f0.w;
    v[4] = (bf16_t)f1.x; v[5] = (bf16_t)f1.y; v[6] = (bf16_t)f1.z; v[7] = (bf16_t)f1.w;
    *(bf16x8*)(x_lds + row * 128 + ((c * 16) ^ ((row & 7) << 4))) = v;
  }
  __syncthreads();  // the only barrier

#pragma unroll
  for (int wi = 0; wi < 3; ++wi) {
    const float* Bp = (wi == 0) ? bq : (wi == 1) ? bk : bv;
    bf16_t* Op      = (wi == 0) ? Qw : Kw;

    bf16x8 wf[2][4];
#pragma unroll
    for (int ct = 0; ct < 4; ++ct)
#pragma unroll
      for (int ks = 0; ks < 2; ++ks)
        wf[ks][ct] = *(const bf16x8*)(w_lds[wi] + (ct * 16 + lo) * 128 +
                                      ((ks * 64 + g * 16) ^ ((lo & 7) << 4)));
    float4 biasv[4];   // Q/K path: bias at e = ct*16 + g*4 + r
    float biass[4];    // V path:   bias at e = ct*16 + lo
    if (wi < 2) {
#pragma unroll
      for (int ct = 0; ct < 4; ++ct)
        biasv[ct] = *(const float4*)(Bp + h * 64 + ct * 16 + g * 4);
    } else {
#pragma unroll
      for (int ct = 0; ct < 4; ++ct) biass[ct] = Bp[h * 64 + ct * 16 + lo];
    }

    const float sc = (wi == 0) ? (0.125f * LOG2E) : 1.0f;
#pragma unroll
    for (int it = 0; it < 4; ++it) {
      const int r0 = it * 64 + w * 16;
      bf16x8 xa[2];
#pragma unroll
      for (int ks = 0; ks < 2; ++ks) {
        const int row = r0 + lo;
        xa[ks] = *(const bf16x8*)(x_lds + row * 128 +
                                  ((ks * 64 + g * 16) ^ ((row & 7) << 4)));
      }
      if (wi < 2) {
        // swapped: D[row=e][col=s]; thread: s = s0+r0+lo, e = ct*16+g*4+r
#pragma unroll
        for (int ct = 0; ct < 4; ++ct) {
          f32x4 a = (f32x4){0.f, 0.f, 0.f, 0.f};
          a = mfma16(wf[0][ct], xa[0], a);
          a = mfma16(wf[1][ct], xa[1], a);
          bf16x4 pk;
#pragma unroll
          for (int r = 0; r < 4; ++r)
            pk[r] = (bf16_t)((a[r] + ((const float*)&biasv[ct])[r]) * sc);
          *(bf16x4*)(Op + ((size_t)bh * SEQ + s0 + r0 + lo) * DHEAD + ct * 16 + g * 4) = pk;
        }
      } else {
        // normal: D[row=s][col=e]; thread: e = ct*16+lo, s = s0+r0+g*4+r -> VT
#pragma unroll
        for (int ct = 0; ct < 4; ++ct) {
          f32x4 a = (f32x4){0.f, 0.f, 0.f, 0.f};
          a = mfma16(xa[0], wf[0][ct], a);
          a = mfma16(xa[1], wf[1][ct], a);
          bf16x4 pk;
#pragma unroll
          for (int r = 0; r < 4; ++r) pk[r] = (bf16_t)(a[r] + biass[ct]);
          *(bf16x4*)(VTw + ((size_t)bh * DHEAD + ct * 16 + lo) * SEQ + s0 + r0 + g * 4) = pk;
        }
      }
    }
  }
}

// ---------------------------------------------------------------------------
// Kernel 2: causal flash attention, split-KV across waves, zero LDS in the
// kv loop. Grid 2048 = one block per (bh, 64-q tile); 4 waves; wave w owns
// kv-slice [w*16, w*16+16) of each 64-kv tile. K/V loaded global->regs;
// P stays in registers (swapped QK^T D-layout == K=16 PV A-layout).
// End-of-block 2-round LDS tree merge of (m, l, O-partial).
// ---------------------------------------------------------------------------
__global__ __launch_bounds__(256) void attn_kernel(
    const bf16_t* __restrict__ Qw, const bf16_t* __restrict__ Kw,
    const bf16_t* __restrict__ VTw, float* __restrict__ Out) {
  __shared__ __align__(16) float o_lds[2][4096];  // two 16KB O-partial buffers
  __shared__ float ml_m[4][64];
  __shared__ float ml_l[4][64];

  const int f = blockIdx.x;
  const int idx = f >> 3;
  const int bh = (f & 7) * 8 + (idx >> 5);  // cluster each bh's tiles on one XCD
  const int qt = 31 - (idx & 31);           // big tiles dispatch first
  const int q0 = qt * 64;
  const int kts = qt + 1;
  const int b = bh >> 4, h = bh & 15;

  const int t = threadIdx.x;
  const int w = t >> 6, lane = t & 63;
  const int lo = lane & 15, g = lane >> 4;

  const bf16_t* Qb = Qw + (size_t)bh * SEQ * DHEAD;
  const bf16_t* Kb = Kw + (size_t)bh * SEQ * DHEAD;
  const bf16_t* Vb = VTw + (size_t)bh * DHEAD * SEQ;

  // Q frags for 4 q-subtiles (B-operand: n=q=ct*16+lo, k=d=ks*32+g*8+i)
  bf16x8 qf[4][2];
#pragma unroll
  for (int ct = 0; ct < 4; ++ct) {
    const bf16_t* qp = Qb + (size_t)(q0 + ct * 16 + lo) * DHEAD + g * 8;
    qf[ct][0] = *(const bf16x8*)(qp);
    qf[ct][1] = *(const bf16x8*)(qp + 32);
  }

  f32x4 oacc[4][4];
  float m[4], l[4];
#pragma unroll
  for (int ct = 0; ct < 4; ++ct) {
    m[ct] = NEGBIG;
    l[ct] = 0.f;
#pragma unroll
    for (int dt = 0; dt < 4; ++dt) oacc[ct][dt] = (f32x4){0.f, 0.f, 0.f, 0.f};
  }

  const int kvw = w * 16;
  // current K-slice A-frags (m=kv=lo, k=d) and V-slice B-frags (k=kv=g*4+i, n=d=lo)
  bf16x8 kc0 = *(const bf16x8*)(Kb + (size_t)(kvw + lo) * DHEAD + g * 8);
  bf16x8 kc1 = *(const bf16x8*)(Kb + (size_t)(kvw + lo) * DHEAD + 32 + g * 8);
  bf16x4 vc0 = *(const bf16x4*)(Vb + (size_t)(0 * 16 + lo) * SEQ + kvw + g * 4);
  bf16x4 vc1 = *(const bf16x4*)(Vb + (size_t)(1 * 16 + lo) * SEQ + kvw + g * 4);
  bf16x4 vc2 = *(const bf16x4*)(Vb + (size_t)(2 * 16 + lo) * SEQ + kvw + g * 4);
  bf16x4 vc3 = *(const bf16x4*)(Vb + (size_t)(3 * 16 + lo) * SEQ + kvw + g * 4);

  for (int kt = 0; kt < kts; ++kt) {
    // QK^T (swapped): D[kv_local=g*4+r][q=ct*16+lo]
    f32x4 sa[4];
    __builtin_amdgcn_s_setprio(1);
#pragma unroll
    for (int ct = 0; ct < 4; ++ct) {
      f32x4 a = (f32x4){0.f, 0.f, 0.f, 0.f};
      a = mfma16(kc0, qf[ct][0], a);
      a = mfma16(kc1, qf[ct][1], a);
      sa[ct] = a;
    }
    __builtin_amdgcn_s_setprio(0);

    // prefetch next tile's slices (no barriers anywhere -> deep overlap)
    bf16x8 kn0, kn1;
    bf16x4 vn0, vn1, vn2, vn3;
    const bool more = (kt + 1 < kts);
    if (more) {
      const int nb = (kt + 1) * 64 + kvw;
      kn0 = *(const bf16x8*)(Kb + (size_t)(nb + lo) * DHEAD + g * 8);
      kn1 = *(const bf16x8*)(Kb + (size_t)(nb + lo) * DHEAD + 32 + g * 8);
      vn0 = *(const bf16x4*)(Vb + (size_t)(0 * 16 + lo) * SEQ + nb + g * 4);
      vn1 = *(const bf16x4*)(Vb + (size_t)(1 * 16 + lo) * SEQ + nb + g * 4);
      vn2 = *(const bf16x4*)(Vb + (size_t)(2 * 16 + lo) * SEQ + nb + g * 4);
      vn3 = *(const bf16x4*)(Vb + (size_t)(3 * 16 + lo) * SEQ + nb + g * 4);
    }

    if (kt == qt) {  // diagonal tile: causal mask (kv global > q global)
#pragma unroll
      for (int ct = 0; ct < 4; ++ct)
#pragma unroll
        for (int r = 0; r < 4; ++r)
          if (kvw + g * 4 + r > ct * 16 + lo) sa[ct][r] = MASKV;
    }

    // online softmax per q-subtile; P stays in registers (log2 domain)
    bf16x4 pa[4];
#pragma unroll
    for (int ct = 0; ct < 4; ++ct) {
      float mt = fmaxf(fmaxf(sa[ct][0], sa[ct][1]), fmaxf(sa[ct][2], sa[ct][3]));
      mt = fmaxf(mt, __shfl_xor(mt, 16));
      mt = fmaxf(mt, __shfl_xor(mt, 32));
      if (__any(mt > m[ct] + 8.f)) {  // defer-max rescale
        const float mn = fmaxf(m[ct], mt);
        const float rs = exp2f(m[ct] - mn);
        l[ct] *= rs;
        m[ct] = mn;
#pragma unroll
        for (int r = 0; r < 4; ++r) {
          const float fr = __shfl(rs, g * 4 + r);
#pragma unroll
          for (int dt = 0; dt < 4; ++dt) oacc[ct][dt][r] *= fr;
        }
      }
      bf16x4 pk;
#pragma unroll
      for (int r = 0; r < 4; ++r) {
        const float pv = exp2f(sa[ct][r] - m[ct]);
        l[ct] += pv;  // per-lane partial; g-reduced once at merge
        pk[r] = (bf16_t)pv;
      }
      pa[ct] = pk;
    }

    // PV: K=16 MFMA, A=P (register), B=V-slice
    __builtin_amdgcn_s_setprio(1);
#pragma unroll
    for (int ct = 0; ct < 4; ++ct) {
      oacc[ct][0] = mfma_k16(pa[ct], vc0, oacc[ct][0]);
      oacc[ct][1] = mfma_k16(pa[ct], vc1, oacc[ct][1]);
      oacc[ct][2] = mfma_k16(pa[ct], vc2, oacc[ct][2]);
      oacc[ct][3] = mfma_k16(pa[ct], vc3, oacc[ct][3]);
    }
    __builtin_amdgcn_s_setprio(0);

    if (more) {
      kc0 = kn0; kc1 = kn1;
      vc0 = vn0; vc1 = vn1; vc2 = vn2; vc3 = vn3;
    }
  }

  // ---- merge the 4 per-wave partial states ----
  // g-reduce l
#pragma unroll
  for (int ct = 0; ct < 4; ++ct) {
    l[ct] += __shfl_xor(l[ct], 16);
    l[ct] += __shfl_xor(l[ct], 32);
  }
  // phase 1: all waves publish (m,l); waves 1,3 publish O
  if (g == 0) {
#pragma unroll
    for (int ct = 0; ct < 4; ++ct) {
      ml_m[w][ct * 16 + lo] = m[ct];
      ml_l[w][ct * 16 + lo] = l[ct];
    }
  }
  if (w & 1) {
    float* ob = o_lds[w >> 1];
#pragma unroll
    for (int ct = 0; ct < 4; ++ct)
#pragma unroll
      for (int dt = 0; dt < 4; ++dt)
        *(f32x4*)(ob + (ct * 4 + dt) * 256 + lane * 4) = oacc[ct][dt];
  }
  __syncthreads();
  // phase 2: waves 0,2 merge partner (w+1), write merged state
  if (!(w & 1)) {
    const int ps = w + 1;
    float* ob = o_lds[w >> 1];
#pragma unroll
    for (int ct = 0; ct < 4; ++ct) {
      const float ma = m[ct];
      const float pm = ml_m[ps][ct * 16 + lo];
      const float pl = ml_l[ps][ct * 16 + lo];
      // per-row factors
      float far[4], fbr[4];
#pragma unroll
      for (int r = 0; r < 4; ++r) {
        const float ma_r = __shfl(ma, g * 4 + r);
        const float pm_r = ml_m[ps][ct * 16 + g * 4 + r];
        const float mn_r = fmaxf(ma_r, pm_r);
        far[r] = exp2f(ma_r - mn_r);
        fbr[r] = exp2f(pm_r - mn_r);
      }
#pragma unroll
      for (int dt = 0; dt < 4; ++dt) {
        const f32x4 obv = *(const f32x4*)(ob + (ct * 4 + dt) * 256 + lane * 4);
#pragma unroll
        for (int r = 0; r < 4; ++r)
          oacc[ct][dt][r] = oacc[ct][dt][r] * far[r] + obv[r] * fbr[r];
      }
      const float mn = fmaxf(ma, pm);
      l[ct] = l[ct] * exp2f(ma - mn) + pl * exp2f(pm - mn);
      m[ct] = mn;
    }
    if (g == 0) {
#pragma unroll
      for (int ct = 0; ct < 4; ++ct) {
        ml_m[w][ct * 16 + lo] = m[ct];
        ml_l[w][ct * 16 + lo] = l[ct];
      }
    }
#pragma unroll
    for (int ct = 0; ct < 4; ++ct)
#pragma unroll
      for (int dt = 0; dt < 4; ++dt)
        *(f32x4*)(ob + (ct * 4 + dt) * 256 + lane * 4) = oacc[ct][dt];
  }
  __syncthreads();
  // phase 3: all waves; wave w outputs d-subtile dt=w for all ct
#pragma unroll
  for (int ct = 0; ct < 4; ++ct) {
    float far[4], fbr[4], inv[4];
#pragma unroll
    for (int r = 0; r < 4; ++r) {
      const float ma_r = ml_m[0][ct * 16 + g * 4 + r];
      const float mb_r = ml_m[2][ct * 16 + g * 4 + r];
      const float mn_r = fmaxf(ma_r, mb_r);
      far[r] = exp2f(ma_r - mn_r);
      fbr[r] = exp2f(mb_r - mn_r);
      const float la_r = ml_l[0][ct * 16 + g * 4 + r];
      const float lb_r = ml_l[2][ct * 16 + g * 4 + r];
      inv[r] = 1.0f / (la_r * far[r] + lb_r * fbr[r]);
    }
    const f32x4 Oa = *(const f32x4*)(o_lds[0] + (ct * 4 + w) * 256 + lane * 4);
    const f32x4 Ob = *(const f32x4*)(o_lds[1] + (ct * 4 + w) * 256 + lane * 4);
#pragma unroll
    for (int r = 0; r < 4; ++r) {
      const float val = (Oa[r] * far[r] + Ob[r] * fbr[r]) * inv[r];
      Out[((size_t)(b * SEQ + q0 + ct * 16 + g * 4 + r)) * DMODEL +
          h * DHEAD + w * 16 + lo] = val;
    }
  }
}

// ---------------------------------------------------------------------------
// Kernel 3: residual add + LayerNorm, in-place on d_out. 1 block per row.
// ---------------------------------------------------------------------------
__global__ __launch_bounds__(256) void ln_kernel(
    const float* __restrict__ x, const float* __restrict__ gamma,
    const float* __restrict__ beta, float* __restrict__ out) {
  __shared__ float red[8];
  const int row = blockIdx.x;
  const int t = threadIdx.x;
  float* orow = out + (size_t)row * DMODEL;
  const float* xrow = x + (size_t)row * DMODEL;

  const float4 o = *(const float4*)(orow + t * 4);
  const float4 xv = *(const float4*)(xrow + t * 4);
  float y0 = o.x + xv.x, y1 = o.y + xv.y, y2 = o.z + xv.z, y3 = o.w + xv.w;
  float s = y0 + y1 + y2 + y3;
  float sq = y0 * y0 + y1 * y1 + y2 * y2 + y3 * y3;
#pragma unroll
  for (int m = 1; m < 64; m <<= 1) {
    s += __shfl_xor(s, m);
    sq += __shfl_xor(sq, m);
  }
  const int w = t >> 6;
  if ((t & 63) == 0) { red[w] = s; red[4 + w] = sq; }
  __syncthreads();
  const float S = red[0] + red[1] + red[2] + red[3];
  const float SQ = red[4] + red[5] + red[6] + red[7];
  const float mu = S * (1.f / DMODEL);
  const float var = SQ * (1.f / DMODEL) - mu * mu;
  const float rstd = rsqrtf(var + 1e-5f);
  const float4 gv = *(const float4*)(gamma + t * 4);
  const float4 bv = *(const float4*)(beta + t * 4);
  float4 res;
  res.x = (y0 - mu) * rstd * gv.x + bv.x;
  res.y = (y1 - mu) * rstd * gv.y + bv.y;
  res.z = (y2 - mu) * rstd * gv.z + bv.z;
  res.w = (y3 - mu) * rstd * gv.w + bv.w;
  *(float4*)(orow + t * 4) = res;
}

// ---------------------------------------------------------------------------
extern "C" void kernel_launch(void* const* d_in, const int* in_sizes, int n_in,
                              void* d_out, int out_size, void* d_ws, size_t ws_size,
                              hipStream_t stream) {
  const float* x     = (const float*)d_in[0];
  const float* Wq    = (const float*)d_in[1];
  const float* bq    = (const float*)d_in[2];
  const float* Wk    = (const float*)d_in[3];
  const float* bk    = (const float*)d_in[4];
  const float* Wv    = (const float*)d_in[5];
  const float* bv    = (const float*)d_in[6];
  const float* gamma = (const float*)d_in[7];
  const float* beta  = (const float*)d_in[8];
  float* out = (float*)d_out;

  const size_t per = (size_t)BHN * SEQ * DHEAD;  // 8388608 elems
  bf16_t* Qw  = (bf16_t*)d_ws;
  bf16_t* Kw  = Qw + per;
  bf16_t* VTw = Kw + per;

  qkv_kernel<<<dim3(8, 64), 256, 0, stream>>>(x, Wq, bq, Wk, bk, Wv, bv, Qw, Kw, VTw);
  attn_kernel<<<dim3(2048), 256, 0, stream>>>(Qw, Kw, VTw, out);
  ln_kernel<<<dim3(8192), 256, 0, stream>>>(x, gamma, beta, out);
}

// Round 7
// 192.338 us; speedup vs baseline: 1.6440x; 1.6440x over previous
//
#include <hip/hip_runtime.h>
#include <hip/hip_bf16.h>

typedef __bf16 bf16_t;
typedef bf16_t bf16x8 __attribute__((ext_vector_type(8)));
typedef bf16_t bf16x4 __attribute__((ext_vector_type(4)));
typedef float f32x4 __attribute__((ext_vector_type(4)));
typedef float f32x16 __attribute__((ext_vector_type(16)));
typedef unsigned int u32;
typedef u32 u32x4 __attribute__((ext_vector_type(4)));

#define SEQ    2048
#define DHEAD  64
#define DMODEL 1024
#define BHN    64   // B*H
#define LOG2E  1.4426950408889634f
#define NEGBIG (-1e30f)
#define MASKV  (-1e38f)

__device__ __forceinline__ f32x4 mfma16(bf16x8 a, bf16x8 b, f32x4 c) {
  return __builtin_amdgcn_mfma_f32_16x16x32_bf16(a, b, c, 0, 0, 0);
}
__device__ __forceinline__ f32x16 mfma32(bf16x8 a, bf16x8 b, f32x16 c) {
  return __builtin_amdgcn_mfma_f32_32x32x16_bf16(a, b, c, 0, 0, 0);
}
__device__ __forceinline__ f32x16 zero16() {
  f32x16 z;
#pragma unroll
  for (int i = 0; i < 16; ++i) z[i] = 0.f;
  return z;
}

// async global->LDS, 16B per lane. dest must be wave-uniform base (HW adds lane*16).
__device__ __forceinline__ void gload16(void* l, const void* g) {
  __builtin_amdgcn_global_load_lds(
      (const __attribute__((address_space(1))) unsigned int*)g,
      (__attribute__((address_space(3))) unsigned int*)l,
      16, 0, 0);
}

// ---------------------------------------------------------------------------
// Kernel 1: per-head QKV projection (unchanged from R5 — passed).
// x [B,S,D] fp32 -> Qw [bh][s][64] bf16 (pre-scaled by log2e/8),
// Kw [bh][s][64], VTw [bh][64][s].
// ---------------------------------------------------------------------------
__global__ __launch_bounds__(256) void qkv_kernel(
    const float* __restrict__ x,
    const float* __restrict__ Wq, const float* __restrict__ bq,
    const float* __restrict__ Wk, const float* __restrict__ bk,
    const float* __restrict__ Wv, const float* __restrict__ bv,
    bf16_t* __restrict__ Qw, bf16_t* __restrict__ Kw, bf16_t* __restrict__ VTw) {
  __shared__ __align__(16) char x_lds[256 * 128];
  __shared__ __align__(16) char w_lds[3][8192];

  const int bh = blockIdx.y;
  const int b = bh >> 4, h = bh & 15;
  const int s0 = blockIdx.x * 256;
  const int t = threadIdx.x;
  const int w = t >> 6, lane = t & 63;
  const int lo = lane & 15, g = lane >> 4;

#pragma unroll
  for (int wi = 0; wi < 3; ++wi) {
    const float* Wp = (wi == 0) ? Wq : (wi == 1) ? Wk : Wv;
    const int d = t >> 2, e0 = (t & 3) * 16;
    const float* wp = Wp + (size_t)(h * 64 + d) * 64 + e0;
    const float4 f0 = *(const float4*)(wp);
    const float4 f1 = *(const float4*)(wp + 4);
    const float4 f2 = *(const float4*)(wp + 8);
    const float4 f3 = *(const float4*)(wp + 12);
    float vals[16];
    vals[0] = f0.x; vals[1] = f0.y; vals[2] = f0.z; vals[3] = f0.w;
    vals[4] = f1.x; vals[5] = f1.y; vals[6] = f1.z; vals[7] = f1.w;
    vals[8] = f2.x; vals[9] = f2.y; vals[10] = f2.z; vals[11] = f2.w;
    vals[12] = f3.x; vals[13] = f3.y; vals[14] = f3.z; vals[15] = f3.w;
#pragma unroll
    for (int j = 0; j < 16; ++j) {
      const int e = e0 + j;
      *(bf16_t*)(w_lds[wi] + e * 128 + ((2 * d) ^ ((e & 7) << 4))) = (bf16_t)vals[j];
    }
  }
#pragma unroll
  for (int p = 0; p < 8; ++p) {
    const int row = p * 32 + (t >> 3);
    const int c = t & 7;
    const float* xp = x + ((size_t)(b * SEQ + s0 + row)) * DMODEL + h * DHEAD + c * 8;
    const float4 f0 = *(const float4*)xp;
    const float4 f1 = *(const float4*)(xp + 4);
    bf16x8 v;
    v[0] = (bf16_t)f0.x; v[1] = (bf16_t)f0.y; v[2] = (bf16_t)f0.z; v[3] = (bf16_t)f0.w;
    v[4] = (bf16_t)f1.x; v[5] = (bf16_t)f1.y; v[6] = (bf16_t)f1.z; v[7] = (bf16_t)f1.w;
    *(bf16x8*)(x_lds + row * 128 + ((c * 16) ^ ((row & 7) << 4))) = v;
  }
  __syncthreads();

#pragma unroll
  for (int wi = 0; wi < 3; ++wi) {
    const float* Bp = (wi == 0) ? bq : (wi == 1) ? bk : bv;
    bf16_t* Op      = (wi == 0) ? Qw : Kw;

    bf16x8 wf[2][4];
#pragma unroll
    for (int ct = 0; ct < 4; ++ct)
#pragma unroll
      for (int ks = 0; ks < 2; ++ks)
        wf[ks][ct] = *(const bf16x8*)(w_lds[wi] + (ct * 16 + lo) * 128 +
                                      ((ks * 64 + g * 16) ^ ((lo & 7) << 4)));
    float4 biasv[4];
    float biass[4];
    if (wi < 2) {
#pragma unroll
      for (int ct = 0; ct < 4; ++ct)
        biasv[ct] = *(const float4*)(Bp + h * 64 + ct * 16 + g * 4);
    } else {
#pragma unroll
      for (int ct = 0; ct < 4; ++ct) biass[ct] = Bp[h * 64 + ct * 16 + lo];
    }

    const float sc = (wi == 0) ? (0.125f * LOG2E) : 1.0f;
#pragma unroll
    for (int it = 0; it < 4; ++it) {
      const int r0 = it * 64 + w * 16;
      bf16x8 xa[2];
#pragma unroll
      for (int ks = 0; ks < 2; ++ks) {
        const int row = r0 + lo;
        xa[ks] = *(const bf16x8*)(x_lds + row * 128 +
                                  ((ks * 64 + g * 16) ^ ((row & 7) << 4)));
      }
      if (wi < 2) {
#pragma unroll
        for (int ct = 0; ct < 4; ++ct) {
          f32x4 a = (f32x4){0.f, 0.f, 0.f, 0.f};
          a = mfma16(wf[0][ct], xa[0], a);
          a = mfma16(wf[1][ct], xa[1], a);
          bf16x4 pk;
#pragma unroll
          for (int r = 0; r < 4; ++r)
            pk[r] = (bf16_t)((a[r] + ((const float*)&biasv[ct])[r]) * sc);
          *(bf16x4*)(Op + ((size_t)bh * SEQ + s0 + r0 + lo) * DHEAD + ct * 16 + g * 4) = pk;
        }
      } else {
#pragma unroll
        for (int ct = 0; ct < 4; ++ct) {
          f32x4 a = (f32x4){0.f, 0.f, 0.f, 0.f};
          a = mfma16(xa[0], wf[0][ct], a);
          a = mfma16(xa[1], wf[1][ct], a);
          bf16x4 pk;
#pragma unroll
          for (int r = 0; r < 4; ++r) pk[r] = (bf16_t)(a[r] + biass[ct]);
          *(bf16x4*)(VTw + ((size_t)bh * DHEAD + ct * 16 + lo) * SEQ + s0 + r0 + g * 4) = pk;
        }
      }
    }
  }
}

// ---------------------------------------------------------------------------
// Kernel 2: causal flash attention, 32x32 MFMA, register-resident P.
// 512 blocks (2/CU), 4 waves x 32 q, KVB=64, pairs (p, 15-p) -> 36 steps.
// LDS: chunked conflict-free layout [d-chunk][row][16B] for K and VT,
// double-buffered gload_lds staging. Softmax fully lane-local (q = lane&31):
// cvt_pk_bf16 + permlane32_swap build PV B-frags in registers (T12).
// ---------------------------------------------------------------------------
__global__ __launch_bounds__(256, 2) void attn_kernel(
    const bf16_t* __restrict__ Qw, const bf16_t* __restrict__ Kw,
    const bf16_t* __restrict__ VTw, float* __restrict__ Out) {
  __shared__ __align__(16) char stage_lds[2][16384];  // [buf]: K 8KB | VT 8KB

  const int f = blockIdx.x;
  const int bh = (f & 7) * 8 + ((f >> 3) & 7);  // cluster 8 bh per XCD
  const int pair = f >> 6;                      // 0..7
  const int b = bh >> 4, h = bh & 15;

  const int t = threadIdx.x;
  const int w = t >> 6, lane = t & 63;
  const int l31 = lane & 31, hi = lane >> 5;

  const char* Kbase = (const char*)(Kw + (size_t)bh * SEQ * DHEAD);   // row = 128B
  const char* Vbase = (const char*)(VTw + (size_t)bh * DHEAD * SEQ);  // row = 4096B
  const bf16_t* Qb = Qw + (size_t)bh * SEQ * DHEAD;

  for (int half = 0; half < 2; ++half) {
    const int qt = half ? (15 - pair) : pair;
    const int qw0 = qt * 128 + w * 32;
    const int qabs = qw0 + l31;   // this lane's q row (one q per lane!)
    const int kts = 2 * qt + 2;

    // Q B-frags: n=q=l31, k = kk*16 + hi*8 + i
    bf16x8 qf[4];
#pragma unroll
    for (int kk = 0; kk < 4; ++kk)
      qf[kk] = *(const bf16x8*)(Qb + (size_t)qabs * DHEAD + kk * 16 + hi * 8);

    float m = NEGBIG, l = 0.f;
    f32x16 oacc[2];
    oacc[0] = zero16();
    oacc[1] = zero16();

    __syncthreads();  // prior reads of buf0 done before restaging
    {
      char* db = &stage_lds[0][0];
#pragma unroll
      for (int p = 0; p < 2; ++p) {
        const int c = w * 2 + p;  // d/kv chunk 0..7
        gload16(db + c * 1024, Kbase + (size_t)lane * 128 + c * 16);
        gload16(db + 8192 + c * 1024, Vbase + (size_t)lane * 4096 + c * 16);
      }
    }
    int cur = 0;
    for (int kt = 0; kt < kts; ++kt) {
      const int kv0 = kt * 64;
      __syncthreads();  // implicit vmcnt(0): tile kt landed; prior buf^1 reads done
      if (kt + 1 < kts) {
        char* db = &stage_lds[cur ^ 1][0];
        const int nk = kv0 + 64;
#pragma unroll
        for (int p = 0; p < 2; ++p) {
          const int c = w * 2 + p;
          gload16(db + c * 1024, Kbase + (size_t)(nk + lane) * 128 + c * 16);
          gload16(db + 8192 + c * 1024,
                  Vbase + (size_t)lane * 4096 + (size_t)nk * 2 + c * 16);
        }
      }
      const bool live0 = (kv0 <= qw0 + 31);
      const bool live1 = (kv0 + 32 <= qw0 + 31);
      if (!live0) { cur ^= 1; continue; }  // wave-uniform; barrier already done
      const char* kb = &stage_lds[cur][0];
      const char* vb = kb + 8192;

      // QK^T swapped: D[m=kv][n=q], q = l31. Chunked LDS reads: conflict-free.
      f32x16 sa0 = zero16(), sa1 = zero16();
      __builtin_amdgcn_s_setprio(1);
#pragma unroll
      for (int kk = 0; kk < 4; ++kk) {
        const bf16x8 kf = *(const bf16x8*)(kb + (kk * 2 + hi) * 1024 + l31 * 16);
        sa0 = mfma32(kf, qf[kk], sa0);
      }
      if (live1) {
#pragma unroll
        for (int kk = 0; kk < 4; ++kk) {
          const bf16x8 kf = *(const bf16x8*)(kb + (kk * 2 + hi) * 1024 + (32 + l31) * 16);
          sa1 = mfma32(kf, qf[kk], sa1);
        }
      }
      __builtin_amdgcn_s_setprio(0);

      // causal mask: reg j holds kv = kvb + (j&3) + 8*(j>>2) + 4*hi
      if (kv0 + 31 > qw0) {
#pragma unroll
        for (int j = 0; j < 16; ++j) {
          const int kvj = kv0 + 4 * hi + ((j & 3) + 8 * (j >> 2));
          if (kvj > qabs) sa0[j] = MASKV;
        }
      }
      if (live1 && kv0 + 63 > qw0) {
#pragma unroll
        for (int j = 0; j < 16; ++j) {
          const int kvj = kv0 + 32 + 4 * hi + ((j & 3) + 8 * (j >> 2));
          if (kvj > qabs) sa1[j] = MASKV;
        }
      }

      // row max (lane-local + partner lane), defer-max rescale
      float mt = NEGBIG;
#pragma unroll
      for (int j = 0; j < 16; ++j) mt = fmaxf(mt, sa0[j]);
      if (live1) {
#pragma unroll
        for (int j = 0; j < 16; ++j) mt = fmaxf(mt, sa1[j]);
      }
      mt = fmaxf(mt, __shfl_xor(mt, 32));
      if (__any(mt > m + 8.f)) {
        const float mn = fmaxf(m, mt);
        const float rs = exp2f(m - mn);
        l *= rs;
        m = mn;
#pragma unroll
        for (int i = 0; i < 16; ++i) { oacc[0][i] *= rs; oacc[1][i] *= rs; }
      }

      // exp2 + pack to bf16 pairs (kv-adjacent), accumulate l (lane-local)
      u32 wds0[8], wds1[8];
      float lt = 0.f;
#pragma unroll
      for (int a2 = 0; a2 < 8; ++a2) {
        const float p0 = exp2f(sa0[2 * a2] - m);
        const float p1 = exp2f(sa0[2 * a2 + 1] - m);
        lt += p0 + p1;
        asm("v_cvt_pk_bf16_f32 %0, %1, %2" : "=v"(wds0[a2]) : "v"(p0), "v"(p1));
      }
      if (live1) {
#pragma unroll
        for (int a2 = 0; a2 < 8; ++a2) {
          const float p0 = exp2f(sa1[2 * a2] - m);
          const float p1 = exp2f(sa1[2 * a2 + 1] - m);
          lt += p0 + p1;
          asm("v_cvt_pk_bf16_f32 %0, %1, %2" : "=v"(wds1[a2]) : "v"(p0), "v"(p1));
        }
      }
      l += lt;

      // permlane32_swap: exchange a_hi <-> b_lo. swap(w0,w2)+swap(w1,w3) turns
      // per-lane P^T regs into exact PV B-frags (k = hi*8 + 2r,2r+1 per word r).
      bf16x8 pb[4];
      {
        asm("v_permlane32_swap_b32 %0, %1" : "+v"(wds0[0]), "+v"(wds0[2]));
        asm("v_permlane32_swap_b32 %0, %1" : "+v"(wds0[1]), "+v"(wds0[3]));
        asm("v_permlane32_swap_b32 %0, %1" : "+v"(wds0[4]), "+v"(wds0[6]));
        asm("v_permlane32_swap_b32 %0, %1" : "+v"(wds0[5]), "+v"(wds0[7]));
        u32x4 b0 = {wds0[0], wds0[1], wds0[2], wds0[3]};
        u32x4 b1 = {wds0[4], wds0[5], wds0[6], wds0[7]};
        pb[0] = __builtin_bit_cast(bf16x8, b0);
        pb[1] = __builtin_bit_cast(bf16x8, b1);
      }
      if (live1) {
        asm("v_permlane32_swap_b32 %0, %1" : "+v"(wds1[0]), "+v"(wds1[2]));
        asm("v_permlane32_swap_b32 %0, %1" : "+v"(wds1[1]), "+v"(wds1[3]));
        asm("v_permlane32_swap_b32 %0, %1" : "+v"(wds1[4]), "+v"(wds1[6]));
        asm("v_permlane32_swap_b32 %0, %1" : "+v"(wds1[5]), "+v"(wds1[7]));
        u32x4 b2 = {wds1[0], wds1[1], wds1[2], wds1[3]};
        u32x4 b3 = {wds1[4], wds1[5], wds1[6], wds1[7]};
        pb[2] = __builtin_bit_cast(bf16x8, b2);
        pb[3] = __builtin_bit_cast(bf16x8, b3);
      }

      // PV: O^T[d][q] += VT-frag x P-frag; chunked VT reads conflict-free
      __builtin_amdgcn_s_setprio(1);
#pragma unroll
      for (int kk = 0; kk < 4; ++kk) {
        if (kk >= 2 && !live1) continue;
#pragma unroll
        for (int dt = 0; dt < 2; ++dt) {
          const bf16x8 vf =
              *(const bf16x8*)(vb + (kk * 2 + hi) * 1024 + (dt * 32 + l31) * 16);
          oacc[dt] = mfma32(vf, pb[kk], oacc[dt]);
        }
      }
      __builtin_amdgcn_s_setprio(0);
      cur ^= 1;
    }

    // epilogue: lane owns q = qabs fully; O row d = dt*32 + 8*rr + 4*hi + 0..3
    const float linv = 1.0f / (l + __shfl_xor(l, 32));
    float* orow = Out + ((size_t)b * SEQ + qabs) * DMODEL + h * DHEAD;
#pragma unroll
    for (int dt = 0; dt < 2; ++dt)
#pragma unroll
      for (int rr = 0; rr < 4; ++rr) {
        float4 v;
        v.x = oacc[dt][rr * 4 + 0] * linv;
        v.y = oacc[dt][rr * 4 + 1] * linv;
        v.z = oacc[dt][rr * 4 + 2] * linv;
        v.w = oacc[dt][rr * 4 + 3] * linv;
        *(float4*)(orow + dt * 32 + rr * 8 + hi * 4) = v;
      }
  }
}

// ---------------------------------------------------------------------------
// Kernel 3: residual add + LayerNorm, in-place on d_out. 1 block per row.
// ---------------------------------------------------------------------------
__global__ __launch_bounds__(256) void ln_kernel(
    const float* __restrict__ x, const float* __restrict__ gamma,
    const float* __restrict__ beta, float* __restrict__ out) {
  __shared__ float red[8];
  const int row = blockIdx.x;
  const int t = threadIdx.x;
  float* orow = out + (size_t)row * DMODEL;
  const float* xrow = x + (size_t)row * DMODEL;

  const float4 o = *(const float4*)(orow + t * 4);
  const float4 xv = *(const float4*)(xrow + t * 4);
  float y0 = o.x + xv.x, y1 = o.y + xv.y, y2 = o.z + xv.z, y3 = o.w + xv.w;
  float s = y0 + y1 + y2 + y3;
  float sq = y0 * y0 + y1 * y1 + y2 * y2 + y3 * y3;
#pragma unroll
  for (int mm = 1; mm < 64; mm <<= 1) {
    s += __shfl_xor(s, mm);
    sq += __shfl_xor(sq, mm);
  }
  const int w = t >> 6;
  if ((t & 63) == 0) { red[w] = s; red[4 + w] = sq; }
  __syncthreads();
  const float S = red[0] + red[1] + red[2] + red[3];
  const float SQ = red[4] + red[5] + red[6] + red[7];
  const float mu = S * (1.f / DMODEL);
  const float var = SQ * (1.f / DMODEL) - mu * mu;
  const float rstd = rsqrtf(var + 1e-5f);
  const float4 gv = *(const float4*)(gamma + t * 4);
  const float4 bv = *(const float4*)(beta + t * 4);
  float4 res;
  res.x = (y0 - mu) * rstd * gv.x + bv.x;
  res.y = (y1 - mu) * rstd * gv.y + bv.y;
  res.z = (y2 - mu) * rstd * gv.z + bv.z;
  res.w = (y3 - mu) * rstd * gv.w + bv.w;
  *(float4*)(orow + t * 4) = res;
}

// ---------------------------------------------------------------------------
extern "C" void kernel_launch(void* const* d_in, const int* in_sizes, int n_in,
                              void* d_out, int out_size, void* d_ws, size_t ws_size,
                              hipStream_t stream) {
  const float* x     = (const float*)d_in[0];
  const float* Wq    = (const float*)d_in[1];
  const float* bq    = (const float*)d_in[2];
  const float* Wk    = (const float*)d_in[3];
  const float* bk    = (const float*)d_in[4];
  const float* Wv    = (const float*)d_in[5];
  const float* bv    = (const float*)d_in[6];
  const float* gamma = (const float*)d_in[7];
  const float* beta  = (const float*)d_in[8];
  float* out = (float*)d_out;

  const size_t per = (size_t)BHN * SEQ * DHEAD;  // 8388608 elems
  bf16_t* Qw  = (bf16_t*)d_ws;
  bf16_t* Kw  = Qw + per;
  bf16_t* VTw = Kw + per;

  qkv_kernel<<<dim3(8, 64), 256, 0, stream>>>(x, Wq, bq, Wk, bk, Wv, bv, Qw, Kw, VTw);
  attn_kernel<<<dim3(512), 256, 0, stream>>>(Qw, Kw, VTw, out);
  ln_kernel<<<dim3(8192), 256, 0, stream>>>(x, gamma, beta, out);
}